// Round 1
// baseline (547.351 us; speedup 1.0000x reference)
//
#include <hip/hip_runtime.h>

#define DK 128
#define HALFK (DK / 2)

// Kernel A: extract (cos, sin) per (position, pair) from the block-diagonal R.
// R[p] layout: R[p, 2k, 2k] = c_k, R[p, 2k+1, 2k] = s_k.
__global__ void build_cs_kernel(const float* __restrict__ R,
                                const int* __restrict__ pos,
                                float2* __restrict__ cs, int seq) {
    int s = blockIdx.x;
    if (s >= seq) return;
    int k = threadIdx.x;           // 0..HALFK-1, one wave
    if (k >= HALFK) return;
    long p = (long)pos[s];
    const float* Rb = R + p * (long)(DK * DK);
    float c  = Rb[(2 * k) * DK + (2 * k)];
    float sn = Rb[(2 * k + 1) * DK + (2 * k)];
    cs[(long)s * HALFK + k] = make_float2(c, sn);
}

// Kernel B: apply rotation. One float4 of x (= 2 pairs) per thread, grid-stride.
__global__ __launch_bounds__(256) void rope_apply_kernel(
        const float4* __restrict__ x4,
        const float2* __restrict__ cs,
        float4* __restrict__ o4,
        unsigned n4, unsigned seq) {
    const unsigned q = DK / 4;     // 32 float4 per d_k row (compile-time -> shifts)
    unsigned stride = gridDim.x * blockDim.x;
    for (unsigned f = blockIdx.x * blockDim.x + threadIdx.x; f < n4; f += stride) {
        unsigned row = f / q;
        unsigned d4  = f % q;
        unsigned s   = row % seq;  // positions repeat every seq rows
        unsigned k0  = d4 * 2;
        float4 xv = x4[f];
        float2 cs0 = cs[(size_t)s * HALFK + k0];
        float2 cs1 = cs[(size_t)s * HALFK + k0 + 1];
        float4 ov;
        ov.x = cs0.x * xv.x - cs0.y * xv.y;
        ov.y = cs0.y * xv.x + cs0.x * xv.y;
        ov.z = cs1.x * xv.z - cs1.y * xv.w;
        ov.w = cs1.y * xv.z + cs1.x * xv.w;
        o4[f] = ov;
    }
}

// Fallback if ws is too small for the cs table: gather c/s straight from R.
// Uncoalesced diagonal reads, but only ~33 MB of unique lines (L2/L3-cached).
__global__ __launch_bounds__(256) void rope_apply_gather_kernel(
        const float4* __restrict__ x4,
        const float* __restrict__ R,
        const int* __restrict__ pos,
        float4* __restrict__ o4,
        unsigned n4, unsigned seq) {
    const unsigned q = DK / 4;
    unsigned stride = gridDim.x * blockDim.x;
    for (unsigned f = blockIdx.x * blockDim.x + threadIdx.x; f < n4; f += stride) {
        unsigned row = f / q;
        unsigned d4  = f % q;
        unsigned s   = row % seq;
        unsigned i0  = d4 * 4;     // first of the 4 dims this thread handles
        long p = (long)pos[s];
        const float* Rb = R + p * (long)(DK * DK);
        float c0 = Rb[(i0 + 0) * DK + (i0 + 0)];
        float s0 = Rb[(i0 + 1) * DK + (i0 + 0)];
        float c1 = Rb[(i0 + 2) * DK + (i0 + 2)];
        float s1 = Rb[(i0 + 3) * DK + (i0 + 2)];
        float4 xv = x4[f];
        float4 ov;
        ov.x = c0 * xv.x - s0 * xv.y;
        ov.y = s0 * xv.x + c0 * xv.y;
        ov.z = c1 * xv.z - s1 * xv.w;
        ov.w = s1 * xv.z + c1 * xv.w;
        o4[f] = ov;
    }
}

extern "C" void kernel_launch(void* const* d_in, const int* in_sizes, int n_in,
                              void* d_out, int out_size, void* d_ws, size_t ws_size,
                              hipStream_t stream) {
    const float* x   = (const float*)d_in[0];
    const int*   pos = (const int*)d_in[1];
    const float* R   = (const float*)d_in[2];
    float* out = (float*)d_out;

    int seq = in_sizes[1];                 // 4096
    unsigned n  = (unsigned)out_size;      // B*H*S*DK
    unsigned n4 = n / 4;

    unsigned blocks = (n4 + 255u) / 256u;
    if (blocks > 2048u) blocks = 2048u;    // grid-stride the rest

    size_t cs_bytes = (size_t)seq * HALFK * sizeof(float2);
    if (ws_size >= cs_bytes) {
        float2* cs = (float2*)d_ws;
        build_cs_kernel<<<seq, HALFK, 0, stream>>>(R, pos, cs, seq);
        rope_apply_kernel<<<blocks, 256, 0, stream>>>(
            (const float4*)x, cs, (float4*)out, n4, (unsigned)seq);
    } else {
        rope_apply_gather_kernel<<<blocks, 256, 0, stream>>>(
            (const float4*)x, R, pos, (float4*)out, n4, (unsigned)seq);
    }
}

// Round 2
// 544.142 us; speedup vs baseline: 1.0059x; 1.0059x over previous
//
#include <hip/hip_runtime.h>

#define DK 128
#define HALFK 64

// Extract (cos, sin) per (position, pair) from block-diagonal R into d_ws.
// R[p, 2k, 2k] = c_k ; R[p, 2k+1, 2k] = s_k.
// cs laid out as float2[seq][64] == float4[seq][32] of (c0,s0,c1,s1) pairs.
__global__ __launch_bounds__(256) void build_cs_kernel(
        const float* __restrict__ R,
        const int* __restrict__ pos,
        float2* __restrict__ cs, int total) {
    int t = blockIdx.x * 256 + threadIdx.x;
    if (t >= total) return;
    int s = t >> 6;            // position index
    int k = t & 63;            // pair index
    long p = (long)pos[s];
    const float* Rb = R + p * (long)(DK * DK);
    float c  = Rb[(2 * k) * DK + (2 * k)];
    float sn = Rb[(2 * k + 1) * DK + (2 * k)];
    cs[(long)s * HALFK + k] = make_float2(c, sn);
}

// Apply rotation: one float4 of x (2 pairs) per thread-iteration, grid-stride.
// seq is a power of two -> mask; cs read as one aligned float4.
__global__ __launch_bounds__(256) void rope_apply_pow2_kernel(
        const float4* __restrict__ x4,
        const float4* __restrict__ cs4,   // [seq][32] = (c0,s0,c1,s1)
        float4* __restrict__ o4,
        unsigned n4, unsigned smask) {
    unsigned stride = gridDim.x * blockDim.x;
    for (unsigned f = blockIdx.x * blockDim.x + threadIdx.x; f < n4; f += stride) {
        unsigned d4 = f & 31u;            // which float4 within the d_k row
        unsigned s  = (f >> 5) & smask;   // position (rows repeat every seq)
        float4 xv = x4[f];
        float4 cv = cs4[(s << 5) | d4];
        float4 ov;
        ov.x = cv.x * xv.x - cv.y * xv.y;
        ov.y = cv.y * xv.x + cv.x * xv.y;
        ov.z = cv.z * xv.z - cv.w * xv.w;
        ov.w = cv.w * xv.z + cv.z * xv.w;
        o4[f] = ov;
    }
}

// Generic fallback (non-pow2 seq): same body with / and %.
__global__ __launch_bounds__(256) void rope_apply_gen_kernel(
        const float4* __restrict__ x4,
        const float4* __restrict__ cs4,
        float4* __restrict__ o4,
        unsigned n4, unsigned seq) {
    unsigned stride = gridDim.x * blockDim.x;
    for (unsigned f = blockIdx.x * blockDim.x + threadIdx.x; f < n4; f += stride) {
        unsigned d4 = f & 31u;
        unsigned s  = (f >> 5) % seq;
        float4 xv = x4[f];
        float4 cv = cs4[(s << 5) | d4];
        float4 ov;
        ov.x = cv.x * xv.x - cv.y * xv.y;
        ov.y = cv.y * xv.x + cv.x * xv.y;
        ov.z = cv.z * xv.z - cv.w * xv.w;
        ov.w = cv.w * xv.z + cv.z * xv.w;
        o4[f] = ov;
    }
}

extern "C" void kernel_launch(void* const* d_in, const int* in_sizes, int n_in,
                              void* d_out, int out_size, void* d_ws, size_t ws_size,
                              hipStream_t stream) {
    const float* x   = (const float*)d_in[0];
    const int*   pos = (const int*)d_in[1];
    const float* R   = (const float*)d_in[2];
    float* out = (float*)d_out;

    int seq = in_sizes[1];                 // 4096
    unsigned n  = (unsigned)out_size;      // B*H*S*DK
    unsigned n4 = n / 4;

    unsigned blocks = (n4 + 255u) / 256u;
    if (blocks > 2048u) blocks = 2048u;    // grid-stride the rest

    float2* cs = (float2*)d_ws;
    int cs_total = seq * HALFK;
    build_cs_kernel<<<(cs_total + 255) / 256, 256, 0, stream>>>(R, pos, cs, cs_total);

    bool pow2 = (seq & (seq - 1)) == 0;
    if (pow2) {
        rope_apply_pow2_kernel<<<blocks, 256, 0, stream>>>(
            (const float4*)x, (const float4*)cs, (float4*)out,
            n4, (unsigned)(seq - 1));
    } else {
        rope_apply_gen_kernel<<<blocks, 256, 0, stream>>>(
            (const float4*)x, (const float4*)cs, (float4*)out,
            n4, (unsigned)seq);
    }
}